// Round 5
// baseline (115.279 us; speedup 1.0000x reference)
//
#include <hip/hip_runtime.h>

#define D 256
#define NV 512
#define NT 512
#define EPS 1e-8f
#define HALF_EPS 5e-9f
#define LN2 0.69314718055994531f

// Taylor of lgamma(x) at 2.5 (s = x - 2.5). Used as
// lgamma(m) = poly(s = m - 0.5) - ln(m*(m+1)), m in (0, 1].
#define C0 0.28468287047291920f
#define C1 0.70315664064524320f
#define C2 0.24517887805011740f
#define C3 (-0.03936734194028790f)
#define C4 0.00932941036738560f
#define C5 (-0.00261463332905590f)
#define C6 0.00080356830356760f

__device__ __forceinline__ float rcpf(float x) { return __builtin_amdgcn_rcpf(x); }

__device__ __forceinline__ float stirling_lgamma(float y) { // y >= 4
    float r = rcpf(y), r2 = r * r;
    float ln = LN2 * __log2f(y);
    return (y - 0.5f) * ln - y + 0.91893853320467f
         + r * (0.08333333333f - 0.00277777778f * r2);
}

__device__ __forceinline__ float stirling_digamma(float y) { // y >= 4
    float r = rcpf(y), r2 = r * r;
    return LN2 * __log2f(y) - 0.5f * r - r2 * (0.08333333333f - 0.00833333333f * r2);
}

// One block per row. Writes psi row + packed float4 [S, A, dgS, 0] where
// A = 0.5*(lgamma(S') - sum lgamma(x')) + 0.25*sum(raw*psi) + 0.25*EPS*sum(psi).
__global__ __launch_bounds__(256) void row_stats(
    const float* __restrict__ va, const float* __restrict__ ta,
    float* __restrict__ dgv, float* __restrict__ dgt,
    float* __restrict__ rv,  float* __restrict__ rt)
{
    int r = blockIdx.x;
    const float* row; float* dgrow; float* sc;
    if (r < NV) { row = va + r * D; dgrow = dgv + r * D; sc = rv + r * 4; }
    else { int q = r - NV; row = ta + q * D; dgrow = dgt + q * D; sc = rt + q * 4; }

    int d = threadIdx.x;
    float raw = row[d];
    float x = raw + EPS;

    float y = x + 4.0f;
    float ry = rcpf(y), ry2 = ry * ry;
    float psi = LN2 * __log2f(y) - 0.5f * ry - ry2 * (0.08333333333f - 0.00833333333f * ry2);
    psi -= rcpf(x) + rcpf(x + 1.0f) + rcpf(x + 2.0f) + rcpf(x + 3.0f);
    dgrow[d] = psi;

    float s = x - 0.5f;
    float q6 = fmaf(C6, s, C5);
    q6 = fmaf(q6, s, C4); q6 = fmaf(q6, s, C3); q6 = fmaf(q6, s, C2); q6 = fmaf(q6, s, C1);
    float g = fmaf(q6, s, C0) - LN2 * __log2f(x * (x + 1.0f));

    float S = raw, G = g, P = raw * psi, W = psi;
    #pragma unroll
    for (int off = 32; off > 0; off >>= 1) {
        S += __shfl_down(S, off, 64);
        G += __shfl_down(G, off, 64);
        P += __shfl_down(P, off, 64);
        W += __shfl_down(W, off, 64);
    }
    __shared__ float red[4][4];
    int wid = d >> 6, lane = d & 63;
    if (lane == 0) { red[0][wid] = S; red[1][wid] = G; red[2][wid] = P; red[3][wid] = W; }
    __syncthreads();
    if (d == 0) {
        float S4 = red[0][0] + red[0][1] + red[0][2] + red[0][3];
        float G4 = red[1][0] + red[1][1] + red[1][2] + red[1][3];
        float P4 = red[2][0] + red[2][1] + red[2][2] + red[2][3];
        float W4 = red[3][0] + red[3][1] + red[3][2] + red[3][3];
        float Se = S4 + 256.0f * EPS;
        float A = 0.5f * (stirling_lgamma(Se) - G4) + 0.25f * P4 + (0.25f * EPS) * W4;
        *(float4*)sc = make_float4(S4, A, stirling_digamma(Se), 0.0f);
    }
}

// 32x32 output tile per block, 256 threads, each thread a 2x2 output block
// (rows r and r+16 on both sides -> shared XOR swizzle since (r+16)&7 == r&7).
// D in 2 width-128 phases; 64 KiB LDS; phase-1 globals prefetched into regs
// during phase-0 compute. LDS reads/result = 0.25 wave-b128 (4x less than R4).
#define PAIR(J,I,V,G,T,H) {                                                   \
    float m0 = V.x + T.x, m1 = V.y + T.y, m2 = V.z + T.z, m3 = V.w + T.w;     \
    float w0 = fmaf(m0,m0,m0), w1 = fmaf(m1,m1,m1);                           \
    float w2 = fmaf(m2,m2,m2), w3 = fmaf(m3,m3,m3);                           \
    accL[J][I] += __log2f((w0 * w1) * (w2 * w3));                             \
    float s0 = m0 - 0.5f, s1 = m1 - 0.5f, s2 = m2 - 0.5f, s3 = m3 - 0.5f;     \
    float q0 = fmaf(C4,s0,C3); q0 = fmaf(q0,s0,C2); q0 = fmaf(q0,s0,C1);      \
    float q1 = fmaf(C4,s1,C3); q1 = fmaf(q1,s1,C2); q1 = fmaf(q1,s1,C1);      \
    float q2 = fmaf(C4,s2,C3); q2 = fmaf(q2,s2,C2); q2 = fmaf(q2,s2,C1);      \
    float q3 = fmaf(C4,s3,C3); q3 = fmaf(q3,s3,C2); q3 = fmaf(q3,s3,C1);      \
    accP[J][I] = fmaf(q0, s0, accP[J][I]); accP[J][I] = fmaf(q1, s1, accP[J][I]); \
    accP[J][I] = fmaf(q2, s2, accP[J][I]); accP[J][I] = fmaf(q3, s3, accP[J][I]); \
    xvt[J][I] = fmaf(T.x, G.x, xvt[J][I]); xvt[J][I] = fmaf(T.y, G.y, xvt[J][I]); \
    xvt[J][I] = fmaf(T.z, G.z, xvt[J][I]); xvt[J][I] = fmaf(T.w, G.w, xvt[J][I]); \
    xtv[J][I] = fmaf(V.x, H.x, xtv[J][I]); xtv[J][I] = fmaf(V.y, H.y, xtv[J][I]); \
    xtv[J][I] = fmaf(V.z, H.z, xtv[J][I]); xtv[J][I] = fmaf(V.w, H.w, xtv[J][I]); }

#define COMPUTE_PHASE()                                                       \
    _Pragma("unroll 4")                                                       \
    for (int c = 0; c < 32; ++c) {                                            \
        int cv = ((c ^ swv) << 2);                                            \
        int ct = ((c ^ swt) << 2);                                            \
        float4 vAx = *(const float4*)(vA + cv);                               \
        float4 vBx = *(const float4*)(vB + cv);                               \
        float4 gAx = *(const float4*)(gA + cv);                               \
        float4 gBx = *(const float4*)(gB + cv);                               \
        float4 tPx = *(const float4*)(tP + ct);                               \
        float4 tQx = *(const float4*)(tQ + ct);                               \
        float4 hPx = *(const float4*)(hP + ct);                               \
        float4 hQx = *(const float4*)(hQ + ct);                               \
        PAIR(0,0, vAx, gAx, tPx, hPx)                                         \
        PAIR(0,1, vAx, gAx, tQx, hQx)                                         \
        PAIR(1,0, vBx, gBx, tPx, hPx)                                         \
        PAIR(1,1, vBx, gBx, tQx, hQx)                                         \
    }

__global__ __launch_bounds__(256, 1) void jsd_pairs(
    const float* __restrict__ va, const float* __restrict__ ta,
    const float* __restrict__ dgv, const float* __restrict__ dgt,
    const float* __restrict__ rv,  const float* __restrict__ rt,
    float* __restrict__ out)
{
    __shared__ float vs[32 * 128];
    __shared__ float gv[32 * 128];
    __shared__ float ts[32 * 128];
    __shared__ float gt[32 * 128];

    const int tid = threadIdx.x;
    const int j0 = blockIdx.x * 32;      // v rows (output cols)
    const int i0 = blockIdx.y * 32;      // t rows (output rows)

    // staging: 4 (row,col) slots per thread per array per phase
    int srowk[4], sgofk[4], sdstk[4];
    #pragma unroll
    for (int k = 0; k < 4; ++k) {
        int q   = tid + (k << 8);
        int row = q >> 5;                // 0..31
        int col = q & 31;                // float4 col 0..31
        srowk[k] = row;
        sgofk[k] = col << 2;
        sdstk[k] = row * 128 + ((col ^ (row & 7)) << 2);
    }

    float4 pv[4], pg[4], pt[4], ph[4];

    // ---- phase 0: load + stage ----
    #pragma unroll
    for (int k = 0; k < 4; ++k) {
        pv[k] = *(const float4*)(va  + (j0 + srowk[k]) * D + sgofk[k]);
        pg[k] = *(const float4*)(dgv + (j0 + srowk[k]) * D + sgofk[k]);
        pt[k] = *(const float4*)(ta  + (i0 + srowk[k]) * D + sgofk[k]);
        ph[k] = *(const float4*)(dgt + (i0 + srowk[k]) * D + sgofk[k]);
    }
    #pragma unroll
    for (int k = 0; k < 4; ++k) {
        float4 a = pv[k], e = pt[k];
        a.x = fmaf(0.5f,a.x,HALF_EPS); a.y = fmaf(0.5f,a.y,HALF_EPS);
        a.z = fmaf(0.5f,a.z,HALF_EPS); a.w = fmaf(0.5f,a.w,HALF_EPS);
        e.x = fmaf(0.5f,e.x,HALF_EPS); e.y = fmaf(0.5f,e.y,HALF_EPS);
        e.z = fmaf(0.5f,e.z,HALF_EPS); e.w = fmaf(0.5f,e.w,HALF_EPS);
        *(float4*)(vs + sdstk[k]) = a;
        *(float4*)(gv + sdstk[k]) = pg[k];
        *(float4*)(ts + sdstk[k]) = e;
        *(float4*)(gt + sdstk[k]) = ph[k];
    }
    // ---- prefetch phase 1 into registers (hidden under phase-0 compute) ----
    #pragma unroll
    for (int k = 0; k < 4; ++k) {
        pv[k] = *(const float4*)(va  + (j0 + srowk[k]) * D + 128 + sgofk[k]);
        pg[k] = *(const float4*)(dgv + (j0 + srowk[k]) * D + 128 + sgofk[k]);
        pt[k] = *(const float4*)(ta  + (i0 + srowk[k]) * D + 128 + sgofk[k]);
        ph[k] = *(const float4*)(dgt + (i0 + srowk[k]) * D + 128 + sgofk[k]);
    }
    __syncthreads();

    const int tj2 = tid & 15;            // j-pair base (j and j+16)
    const int ti2 = tid >> 4;            // i-pair base (i and i+16)
    const int swv = tj2 & 7;
    const int swt = ti2 & 7;
    const float* vA = vs + tj2 * 128;        const float* vB = vs + (tj2 + 16) * 128;
    const float* gA = gv + tj2 * 128;        const float* gB = gv + (tj2 + 16) * 128;
    const float* tP = ts + ti2 * 128;        const float* tQ = ts + (ti2 + 16) * 128;
    const float* hP = gt + ti2 * 128;        const float* hQ = gt + (ti2 + 16) * 128;

    float accP[2][2] = {}, accL[2][2] = {}, xvt[2][2] = {}, xtv[2][2] = {};

    COMPUTE_PHASE();                     // phase 0

    __syncthreads();
    #pragma unroll
    for (int k = 0; k < 4; ++k) {
        float4 a = pv[k], e = pt[k];
        a.x = fmaf(0.5f,a.x,HALF_EPS); a.y = fmaf(0.5f,a.y,HALF_EPS);
        a.z = fmaf(0.5f,a.z,HALF_EPS); a.w = fmaf(0.5f,a.w,HALF_EPS);
        e.x = fmaf(0.5f,e.x,HALF_EPS); e.y = fmaf(0.5f,e.y,HALF_EPS);
        e.z = fmaf(0.5f,e.z,HALF_EPS); e.w = fmaf(0.5f,e.w,HALF_EPS);
        *(float4*)(vs + sdstk[k]) = a;
        *(float4*)(gv + sdstk[k]) = pg[k];
        *(float4*)(ts + sdstk[k]) = e;
        *(float4*)(gt + sdstk[k]) = ph[k];
    }
    __syncthreads();

    COMPUTE_PHASE();                     // phase 1

    // ---- epilogue: 2x2 outputs ----
    #pragma unroll
    for (int jj = 0; jj < 2; ++jj) {
        int j = j0 + tj2 + jj * 16;
        float4 RJ = *(const float4*)(rv + j * 4);
        #pragma unroll
        for (int ii = 0; ii < 2; ++ii) {
            int i = i0 + ti2 + ii * 16;
            float4 RI = *(const float4*)(rt + i * 4);
            float accg = accP[jj][ii] + 256.0f * C0 - LN2 * accL[jj][ii];
            float Sm = fmaf(0.5f, RJ.x + RI.x, 256.0f * EPS);
            float jsd = accg - stirling_lgamma(Sm) + RJ.y + RI.y
                      - 0.5f * (xvt[jj][ii] + xtv[jj][ii])
                      + 0.25f * (RJ.x - RI.x) * (RI.z - RJ.z);
            out[i * 512 + j] = 1.0f - jsd;
        }
    }
}

extern "C" void kernel_launch(void* const* d_in, const int* in_sizes, int n_in,
                              void* d_out, int out_size, void* d_ws, size_t ws_size,
                              hipStream_t stream) {
    const float* va = (const float*)d_in[0];
    const float* ta = (const float*)d_in[1];
    float* ws  = (float*)d_ws;
    float* dgv = ws;
    float* dgt = ws + NV * D;
    float* rv  = ws + (NV + NT) * D;
    float* rt  = rv + NV * 4;
    float* out = (float*)d_out;

    row_stats<<<NV + NT, 256, 0, stream>>>(va, ta, dgv, dgt, rv, rt);
    jsd_pairs<<<dim3(16, 16), 256, 0, stream>>>(va, ta, dgv, dgt, rv, rt, out);
}

// Round 6
// 71.788 us; speedup vs baseline: 1.6058x; 1.6058x over previous
//
#include <hip/hip_runtime.h>

#define D 256
#define NV 512
#define NT 512
#define EPS 1e-8f
#define HALF_EPS 5e-9f
#define LN2 0.69314718055994531f

// Taylor of lgamma at 2.5 (for row_stats deg-6 path)
#define C0 0.28468287047291920f
#define C1 0.70315664064524320f
#define C2 0.24517887805011740f
#define C3 (-0.03936734194028790f)
#define C4 0.00932941036738560f
#define C5 (-0.00261463332905590f)
#define C6 0.00080356830356760f
// Chebyshev-economized quadratic on s in [-1/2,1/2]:
//   C1E = C1 + (3/16)C3, C2E = C2 + C4/4, C0E = C0 - C4/128; |err| <= ~1.4e-3/elem
#define C0E 0.28460998445f
#define C1E 0.69577526404f
#define C2E 0.24751123064f

#define LSTRIDE 68   // 64 floats + 4 pad: imm-offset ds_read_b128, benign banks

__device__ __forceinline__ float rcpf(float x) { return __builtin_amdgcn_rcpf(x); }

__device__ __forceinline__ float stirling_lgamma(float y) { // y >= 4
    float r = rcpf(y), r2 = r * r;
    float ln = LN2 * __log2f(y);
    return (y - 0.5f) * ln - y + 0.91893853320467f
         + r * (0.08333333333f - 0.00277777778f * r2);
}

__device__ __forceinline__ float stirling_digamma(float y) { // y >= 4
    float r = rcpf(y), r2 = r * r;
    return LN2 * __log2f(y) - 0.5f * r - r2 * (0.08333333333f - 0.00833333333f * r2);
}

// One block per row. Writes psi row + packed float4 [S, A, dgS, 0] where
// A = 0.5*(lgamma(S') - sum lgamma(x')) + 0.25*sum(raw*psi) + 0.25*EPS*sum(psi).
__global__ __launch_bounds__(256) void row_stats(
    const float* __restrict__ va, const float* __restrict__ ta,
    float* __restrict__ dgv, float* __restrict__ dgt,
    float* __restrict__ rv,  float* __restrict__ rt)
{
    int r = blockIdx.x;
    const float* row; float* dgrow; float* sc;
    if (r < NV) { row = va + r * D; dgrow = dgv + r * D; sc = rv + r * 4; }
    else { int q = r - NV; row = ta + q * D; dgrow = dgt + q * D; sc = rt + q * 4; }

    int d = threadIdx.x;
    float raw = row[d];
    float x = raw + EPS;

    float y = x + 4.0f;
    float ry = rcpf(y), ry2 = ry * ry;
    float psi = LN2 * __log2f(y) - 0.5f * ry - ry2 * (0.08333333333f - 0.00833333333f * ry2);
    psi -= rcpf(x) + rcpf(x + 1.0f) + rcpf(x + 2.0f) + rcpf(x + 3.0f);
    dgrow[d] = psi;

    float s = x - 0.5f;
    float q6 = fmaf(C6, s, C5);
    q6 = fmaf(q6, s, C4); q6 = fmaf(q6, s, C3); q6 = fmaf(q6, s, C2); q6 = fmaf(q6, s, C1);
    float g = fmaf(q6, s, C0) - LN2 * __log2f(x * (x + 1.0f));

    float S = raw, G = g, P = raw * psi, W = psi;
    #pragma unroll
    for (int off = 32; off > 0; off >>= 1) {
        S += __shfl_down(S, off, 64);
        G += __shfl_down(G, off, 64);
        P += __shfl_down(P, off, 64);
        W += __shfl_down(W, off, 64);
    }
    __shared__ float red[4][4];
    int wid = d >> 6, lane = d & 63;
    if (lane == 0) { red[0][wid] = S; red[1][wid] = G; red[2][wid] = P; red[3][wid] = W; }
    __syncthreads();
    if (d == 0) {
        float S4 = red[0][0] + red[0][1] + red[0][2] + red[0][3];
        float G4 = red[1][0] + red[1][1] + red[1][2] + red[1][3];
        float P4 = red[2][0] + red[2][1] + red[2][2] + red[2][3];
        float W4 = red[3][0] + red[3][1] + red[3][2] + red[3][3];
        float Se = S4 + 256.0f * EPS;
        float A = 0.5f * (stirling_lgamma(Se) - G4) + 0.25f * P4 + (0.25f * EPS) * W4;
        *(float4*)sc = make_float4(S4, A, stirling_digamma(Se), 0.0f);
    }
}

// 16x16 tile, 256 threads (1 result each), grid 32x32 = 1024 blocks (4/CU).
// D in 4 width-64 phases, padded-stride LDS (imm-offset b128 reads, no XOR).
// Per elem: m add, M2 fma, w fma, 2 dot fma, ~1 log-chain op = 6 VALU + 1/4 trans.
// Sum(m) is NOT accumulated: = 0.5*(Sv+St)+256eps from row scalars.
__global__ __launch_bounds__(256, 4) void jsd_pairs(
    const float* __restrict__ va, const float* __restrict__ ta,
    const float* __restrict__ dgv, const float* __restrict__ dgt,
    const float* __restrict__ rv,  const float* __restrict__ rt,
    float* __restrict__ out)
{
    __shared__ float vs[16 * LSTRIDE];
    __shared__ float gv[16 * LSTRIDE];
    __shared__ float ts[16 * LSTRIDE];
    __shared__ float gt[16 * LSTRIDE];

    const int tid = threadIdx.x;
    const int j0 = blockIdx.x * 16;      // v rows (output cols)
    const int i0 = blockIdx.y * 16;      // t rows (output rows)

    const int tj = tid & 15;             // = staging col
    const int ti = tid >> 4;             // = staging row

    const float* vp = vs + tj * LSTRIDE;
    const float* gp = gv + tj * LSTRIDE;
    const float* tp = ts + ti * LSTRIDE;
    const float* hp = gt + ti * LSTRIDE;
    const int ldst = ti * LSTRIDE + (tj << 2);

    float accM2a = 0.0f, accM2b = 0.0f;
    float accLa = 0.0f, accLb = 0.0f;
    float xsa = 0.0f, xsb = 0.0f;

    for (int h = 0; h < 4; ++h) {
        if (h) __syncthreads();
        {
            int goff = (h << 6) + (tj << 2);
            float4 a = *(const float4*)(va  + (j0 + ti) * D + goff);
            float4 b = *(const float4*)(dgv + (j0 + ti) * D + goff);
            float4 e = *(const float4*)(ta  + (i0 + ti) * D + goff);
            float4 f = *(const float4*)(dgt + (i0 + ti) * D + goff);
            a.x = fmaf(0.5f, a.x, HALF_EPS); a.y = fmaf(0.5f, a.y, HALF_EPS);
            a.z = fmaf(0.5f, a.z, HALF_EPS); a.w = fmaf(0.5f, a.w, HALF_EPS);
            e.x = fmaf(0.5f, e.x, HALF_EPS); e.y = fmaf(0.5f, e.y, HALF_EPS);
            e.z = fmaf(0.5f, e.z, HALF_EPS); e.w = fmaf(0.5f, e.w, HALF_EPS);
            *(float4*)(vs + ldst) = a;
            *(float4*)(gv + ldst) = b;
            *(float4*)(ts + ldst) = e;
            *(float4*)(gt + ldst) = f;
        }
        __syncthreads();

        #pragma unroll
        for (int c = 0; c < 16; ++c) {
            float4 v4 = *(const float4*)(vp + (c << 2));
            float4 g4 = *(const float4*)(gp + (c << 2));
            float4 t4 = *(const float4*)(tp + (c << 2));
            float4 h4 = *(const float4*)(hp + (c << 2));

            float m0 = v4.x + t4.x, m1 = v4.y + t4.y;
            float m2 = v4.z + t4.z, m3 = v4.w + t4.w;

            accM2a = fmaf(m0, m0, accM2a); accM2b = fmaf(m1, m1, accM2b);
            accM2a = fmaf(m2, m2, accM2a); accM2b = fmaf(m3, m3, accM2b);

            float w0 = fmaf(m0, m0, m0), w1 = fmaf(m1, m1, m1);
            float w2 = fmaf(m2, m2, m2), w3 = fmaf(m3, m3, m3);
            float lg = __log2f((w0 * w1) * (w2 * w3));
            if (c & 1) accLb += lg; else accLa += lg;

            xsa = fmaf(t4.x, g4.x, xsa); xsb = fmaf(t4.y, g4.y, xsb);
            xsa = fmaf(t4.z, g4.z, xsa); xsb = fmaf(t4.w, g4.w, xsb);
            xsa = fmaf(v4.x, h4.x, xsa); xsb = fmaf(v4.y, h4.y, xsb);
            xsa = fmaf(v4.z, h4.z, xsa); xsb = fmaf(v4.w, h4.w, xsb);
        }
    }

    const int j = j0 + tj, i = i0 + ti;
    float4 RJ = *(const float4*)(rv + j * 4);
    float4 RI = *(const float4*)(rt + i * 4);
    float Sv = RJ.x, Av = RJ.y, dgSv = RJ.z;
    float St = RI.x, At = RI.y, dgSt = RI.z;

    float M1 = fmaf(0.5f, Sv + St, 256.0f * EPS);  // = sum over d of m_d = Sm'
    float S1 = M1 - 128.0f;                        // sum of s = m - 0.5
    float S2 = (accM2a + accM2b) - M1 + 64.0f;     // sum of s^2
    float sumlg = fmaf(C1E, S1, 256.0f * C0E) + C2E * S2 - LN2 * (accLa + accLb);

    float jsd = sumlg - stirling_lgamma(M1) + Av + At
              - 0.5f * (xsa + xsb)
              + 0.25f * (Sv - St) * (dgSt - dgSv);

    out[i * 512 + j] = 1.0f - jsd;
}

extern "C" void kernel_launch(void* const* d_in, const int* in_sizes, int n_in,
                              void* d_out, int out_size, void* d_ws, size_t ws_size,
                              hipStream_t stream) {
    const float* va = (const float*)d_in[0];
    const float* ta = (const float*)d_in[1];
    float* ws  = (float*)d_ws;
    float* dgv = ws;
    float* dgt = ws + NV * D;
    float* rv  = ws + (NV + NT) * D;
    float* rt  = rv + NV * 4;
    float* out = (float*)d_out;

    row_stats<<<NV + NT, 256, 0, stream>>>(va, ta, dgv, dgt, rv, rt);
    jsd_pairs<<<dim3(32, 32), 256, 0, stream>>>(va, ta, dgv, dgt, rv, rt, out);
}